// Round 1
// 569.299 us; speedup vs baseline: 1.0027x; 1.0027x over previous
//
#include <hip/hip_runtime.h>
#include <stdint.h>

#define B_ 8
#define N_ 8192
#define DIM_ 512
#define H_ 8
#define DH_ 64
#define ROWS (B_*N_)        // 65536
#define TRIPLE (3*DIM_)     // 1536
#define EPS_ 1e-5f

typedef __attribute__((ext_vector_type(8))) short short8;
typedef __attribute__((ext_vector_type(4))) float f32x4;
typedef __attribute__((ext_vector_type(4))) float fl4;
typedef __attribute__((ext_vector_type(4))) unsigned short us4;
typedef __attribute__((ext_vector_type(8))) unsigned short us8;

#define AS1 __attribute__((address_space(1)))
#define AS3 __attribute__((address_space(3)))

__device__ __forceinline__ void gld16(const void* g, void* l) {
    // async global->LDS, 16B/lane; LDS dest = wave-uniform base + lane*16
    __builtin_amdgcn_global_load_lds((const AS1 void*)(uintptr_t)g,
                                     (AS3 void*)(unsigned)(uintptr_t)l, 16, 0, 0);
}

__device__ inline unsigned short f2bf(float f) {
    union { float f; unsigned int u; } x; x.f = f;
    unsigned int r = x.u + 0x7fffu + ((x.u >> 16) & 1u);
    return (unsigned short)(r >> 16);
}
__device__ inline float bf2f(unsigned short b) {
    union { unsigned int u; float f; } x; x.u = ((unsigned int)b) << 16;
    return x.f;
}

// ---------------------------------------------------------------------------
// k_cvt: x fp32 -> bf16 (row-major unchanged), enables async A-staging in k_qkv
__global__ __launch_bounds__(256) void k_cvt(const float* __restrict__ x,
                                             unsigned short* __restrict__ xb) {
    size_t i = ((size_t)blockIdx.x * 256 + threadIdx.x) * 8;
    fl4 a = *(const fl4*)(x + i);
    fl4 b = *(const fl4*)(x + i + 4);
    us8 r;
    r[0] = f2bf(a[0]); r[1] = f2bf(a[1]); r[2] = f2bf(a[2]); r[3] = f2bf(a[3]);
    r[4] = f2bf(b[0]); r[5] = f2bf(b[1]); r[6] = f2bf(b[2]); r[7] = f2bf(b[3]);
    *(us8*)(xb + i) = r;
}

// ---------------------------------------------------------------------------
// k_prep: transpose+convert weights to bf16 [n][k]
__global__ void k_prep(const float* __restrict__ w_qkv, const float* __restrict__ w_out,
                       unsigned short* __restrict__ wqkvT, unsigned short* __restrict__ woutT) {
    int idx = blockIdx.x * 256 + threadIdx.x;
    if (idx < TRIPLE * DIM_) {
        int n = idx / DIM_, k = idx - n * DIM_;
        wqkvT[idx] = f2bf(w_qkv[(size_t)k * TRIPLE + n]);
    }
    if (idx < DIM_ * DIM_) {
        int n = idx / DIM_, k = idx - n * DIM_;
        woutT[idx] = f2bf(w_out[(size_t)k * DIM_ + n]);
    }
}

// ---------------------------------------------------------------------------
// k_qkv8: 256x256-tile 8-phase GEMM (m201 template, plain HIP).
//   C[65536x1536] = relu-mask( xb[65536x512] @ wT^T ), bf16 out.
//   BK=64, 8 waves (2Mx4N), per-wave C = 128x64, LDS 128KiB (2 K-tile dbuf).
//   st_16x32 LDS swizzle: [row/16][col/32] subtiles of 1024B,
//     byte_in_subtile = (row&15)*64 + ((col&31)*2 ^ ((row&8)?32:0))
//   Staging: global_load_lds w=16, LINEAR dest; swizzle applied on the
//   per-lane GLOBAL source address (both-sides rule), swizzled ds_read addr.
//   Pipeline: tile t+1 staged at phase0 of iter t (8 loads/thread), waited
//   only at end of phase3 (lead ~4 MFMA phases); raw s_barrier (no vmcnt
//   drain at barriers). s_setprio(1) around each 16-MFMA cluster.
__global__ __launch_bounds__(512, 2) void k_qkv8(const unsigned short* __restrict__ xb,
        const unsigned short* __restrict__ wT,      // [1536][512] bf16
        unsigned short* __restrict__ qkv)           // [65536][1536] bf16
{
    __shared__ __align__(1024) unsigned short Ab[2][16384];   // 2 x 256x64
    __shared__ __align__(1024) unsigned short Bb[2][16384];

    const int tid  = threadIdx.x;
    const int lane = tid & 63;
    const int wid  = tid >> 6;     // 0..7
    const int wr   = wid >> 2;     // 0..1  (M half)
    const int wc   = wid & 3;      // 0..3  (N quarter)
    const int lr   = lane & 15;

    // bijective XCD swizzle (1536 % 8 == 0): group the 6 N-blocks sharing an
    // A-panel onto one XCD's L2.
    int id  = blockIdx.x;
    int nid = (id & 7) * 192 + (id >> 3);
    int n0  = (nid % 6) * 256;
    int m0  = (nid / 6) * 256;

    // ---- staging source coords. slot s covers LDS bytes [s*16, s*16+16);
    // invert the subtile+swizzle layout to get the logical (row, col) whose
    // 8 contiguous bf16 land there.
    const unsigned short* pA[4];
    const unsigned short* pB[4];
    unsigned ldst[4];
#pragma unroll
    for (int j = 0; j < 4; ++j) {
        int s    = tid + j * 512;
        int row  = ((s >> 7) << 4) + ((s >> 2) & 15);
        int colb = ((s & 3) << 4) ^ (((s >> 5) & 1) << 5);
        int col  = ((s >> 6) & 1) * 32 + (colb >> 1);
        pA[j] = xb + (size_t)(m0 + row) * 512 + col;
        pB[j] = wT + (size_t)(n0 + row) * 512 + col;
        ldst[j] = (unsigned)((j * 512 + wid * 64) * 8);  // ushort idx, linear dest
    }
    // swizzled ds_read lane offset (ushort idx within a 1024B subtile row set)
    const int lo = lr * 32 + ((((lane >> 4) << 4) ^ ((lr >> 3) << 5)) >> 1);

    auto STAGE = [&](int t, int c) {
#pragma unroll
        for (int j = 0; j < 4; ++j) {
            gld16(pA[j] + t * 64, (void*)&Ab[c][ldst[j]]);
            gld16(pB[j] + t * 64, (void*)&Bb[c][ldst[j]]);
        }
    };

    f32x4 acc[8][4] = {};
    short8 af[4][2], bf0[2][2], bf1[2][2];

    STAGE(0, 0);
    asm volatile("s_waitcnt vmcnt(0)" ::: "memory");
    __builtin_amdgcn_s_barrier();

    for (int t = 0; t < 8; ++t) {
        const int cur = t & 1;
        const unsigned short* Ac = Ab[cur];
        const unsigned short* Bc = Bb[cur];

        // ---------------- P0: prefetch tile t+1; compute (mh0 x nh0)
        if (t < 7) STAGE(t + 1, cur ^ 1);
#pragma unroll
        for (int m = 0; m < 4; ++m)
#pragma unroll
            for (int ks = 0; ks < 2; ++ks)
                af[m][ks] = *(const short8*)&Ac[(wr * 16 + m * 2 + ks) * 512 + lo];
#pragma unroll
        for (int n = 0; n < 2; ++n)
#pragma unroll
            for (int ks = 0; ks < 2; ++ks)
                bf0[n][ks] = *(const short8*)&Bc[((wc * 4 + n) * 2 + ks) * 512 + lo];
        __builtin_amdgcn_s_barrier();
        __builtin_amdgcn_s_setprio(1);
#pragma unroll
        for (int m = 0; m < 4; ++m)
#pragma unroll
            for (int n = 0; n < 2; ++n)
#pragma unroll
                for (int ks = 0; ks < 2; ++ks)
                    acc[m][n] = __builtin_amdgcn_mfma_f32_16x16x32_bf16(af[m][ks], bf0[n][ks], acc[m][n], 0, 0, 0);
        __builtin_amdgcn_s_setprio(0);
        __builtin_amdgcn_s_barrier();

        // ---------------- P1: (mh0 x nh1)
#pragma unroll
        for (int n = 0; n < 2; ++n)
#pragma unroll
            for (int ks = 0; ks < 2; ++ks)
                bf1[n][ks] = *(const short8*)&Bc[((wc * 4 + 2 + n) * 2 + ks) * 512 + lo];
        __builtin_amdgcn_s_barrier();
        __builtin_amdgcn_s_setprio(1);
#pragma unroll
        for (int m = 0; m < 4; ++m)
#pragma unroll
            for (int n = 0; n < 2; ++n)
#pragma unroll
                for (int ks = 0; ks < 2; ++ks)
                    acc[m][2 + n] = __builtin_amdgcn_mfma_f32_16x16x32_bf16(af[m][ks], bf1[n][ks], acc[m][2 + n], 0, 0, 0);
        __builtin_amdgcn_s_setprio(0);
        __builtin_amdgcn_s_barrier();

        // ---------------- P2: (mh1 x nh1) — reload A frags for rows 64..127
#pragma unroll
        for (int m = 0; m < 4; ++m)
#pragma unroll
            for (int ks = 0; ks < 2; ++ks)
                af[m][ks] = *(const short8*)&Ac[(wr * 16 + (4 + m) * 2 + ks) * 512 + lo];
        __builtin_amdgcn_s_barrier();
        __builtin_amdgcn_s_setprio(1);
#pragma unroll
        for (int m = 0; m < 4; ++m)
#pragma unroll
            for (int n = 0; n < 2; ++n)
#pragma unroll
                for (int ks = 0; ks < 2; ++ks)
                    acc[4 + m][2 + n] = __builtin_amdgcn_mfma_f32_16x16x32_bf16(af[m][ks], bf1[n][ks], acc[4 + m][2 + n], 0, 0, 0);
        __builtin_amdgcn_s_setprio(0);
        __builtin_amdgcn_s_barrier();

        // ---------------- P3: (mh1 x nh0) — re-read nh0 B frags; then publish t+1
#pragma unroll
        for (int n = 0; n < 2; ++n)
#pragma unroll
            for (int ks = 0; ks < 2; ++ks)
                bf0[n][ks] = *(const short8*)&Bc[((wc * 4 + n) * 2 + ks) * 512 + lo];
        __builtin_amdgcn_s_barrier();
        __builtin_amdgcn_s_setprio(1);
#pragma unroll
        for (int m = 0; m < 4; ++m)
#pragma unroll
            for (int n = 0; n < 2; ++n)
#pragma unroll
                for (int ks = 0; ks < 2; ++ks)
                    acc[4 + m][n] = __builtin_amdgcn_mfma_f32_16x16x32_bf16(af[m][ks], bf0[n][ks], acc[4 + m][n], 0, 0, 0);
        __builtin_amdgcn_s_setprio(0);
        if (t < 7) asm volatile("s_waitcnt vmcnt(0)" ::: "memory"); // tile t+1 landed
        __builtin_amdgcn_s_barrier();                               // ...in all waves
    }

    // epilogue: relu on q,k columns (col<1024), bf16 store
#pragma unroll
    for (int m = 0; m < 8; ++m) {
        int row = m0 + wr * 128 + m * 16 + ((lane >> 4) << 2);
#pragma unroll
        for (int n = 0; n < 4; ++n) {
            int col = n0 + wc * 64 + n * 16 + (lane & 15);
            bool rl = (col < 1024);
#pragma unroll
            for (int r = 0; r < 4; ++r) {
                float v = acc[m][n][r];
                if (rl && v < 0.0f) v = 0.0f;
                qkv[(size_t)(row + r) * TRIPLE + col] = f2bf(v);
            }
        }
    }
}

// ---------------------------------------------------------------------------
// k_qkv_f: fallback (round-1 kernel) if ws too small for bf16 x copy.
__global__ __launch_bounds__(256) void k_qkv_f(const float* __restrict__ x,
        const unsigned short* __restrict__ wT,
        unsigned short* __restrict__ qkv)
{
    __shared__ unsigned short As[128][40];
    __shared__ unsigned short Bs[128][40];
    int t = threadIdx.x;
    int lane = t & 63, wave = t >> 6;
    int m0 = blockIdx.y * 128;
    int n0 = blockIdx.x * 128;
    int wm = (wave & 1) * 64, wn = (wave >> 1) * 64;
    int lr = lane & 15, kg = (lane >> 4) * 8;

    f32x4 acc[4][4] = {};
    for (int k0 = 0; k0 < DIM_; k0 += 32) {
#pragma unroll
        for (int i = 0; i < 4; ++i) {
            int c = t + 256 * i;
            int r = c >> 3, c4 = (c & 7) * 4;
            fl4 v = *(const fl4*)(x + (size_t)(m0 + r) * DIM_ + k0 + c4);
            unsigned short* dst = &As[r][c4];
            dst[0] = f2bf(v[0]); dst[1] = f2bf(v[1]); dst[2] = f2bf(v[2]); dst[3] = f2bf(v[3]);
        }
#pragma unroll
        for (int i = 0; i < 2; ++i) {
            int c = t + 256 * i;
            int r = c >> 2, c8 = (c & 3) * 8;
            *(int4*)&Bs[r][c8] = *(const int4*)(wT + (size_t)(n0 + r) * DIM_ + k0 + c8);
        }
        __syncthreads();
        short8 af[4], bfr[4];
#pragma unroll
        for (int i = 0; i < 4; ++i) af[i]  = *(short8*)&As[wm + i*16 + lr][kg];
#pragma unroll
        for (int j = 0; j < 4; ++j) bfr[j] = *(short8*)&Bs[wn + j*16 + lr][kg];
#pragma unroll
        for (int i = 0; i < 4; ++i)
#pragma unroll
            for (int j = 0; j < 4; ++j)
                acc[i][j] = __builtin_amdgcn_mfma_f32_16x16x32_bf16(af[i], bfr[j], acc[i][j], 0, 0, 0);
        __syncthreads();
    }
#pragma unroll
    for (int i = 0; i < 4; ++i) {
        int row = m0 + wm + i*16 + (lane >> 4) * 4;
#pragma unroll
        for (int j = 0; j < 4; ++j) {
            int col = n0 + wn + j*16 + (lane & 15);
            bool rl = (col < 1024);
#pragma unroll
            for (int r = 0; r < 4; ++r) {
                float v = acc[i][j][r];
                if (rl && v < 0.0f) v = 0.0f;
                qkv[(size_t)(row + r) * TRIPLE + col] = f2bf(v);
            }
        }
    }
}

// ---------------------------------------------------------------------------
// k_kv: kv[b,h] (64x64) = sum_n relu(k)[n][m] * v[n][d].
__global__ __launch_bounds__(256) void k_kv(const unsigned short* __restrict__ qkv,
                                            float* __restrict__ kv) // [64][64][64] fp32
{
    __shared__ unsigned short KT[64][136];
    __shared__ unsigned short VT[64][136];
    __shared__ float red[64 * 64];
    int t = threadIdx.x, lane = t & 63, wave = t >> 6;
    int bh = blockIdx.x;
    int b = bh >> 3, h = bh & 7;
    int chunk = blockIdx.y;
    size_t rowbase = (size_t)b * N_ + (size_t)chunk * 1024;
    int kcol = DIM_ + h * 64;
    int vcol = 2 * DIM_ + h * 64;
    int lr = lane & 15;

    f32x4 acc[4][4] = {};
    for (int tile = 0; tile < 8; ++tile) {
        size_t r0 = rowbase + tile * 128;
#pragma unroll
        for (int i = 0; i < 8; ++i) {
            int c = t + 256 * i;
            int r = c >> 4, f4 = (c & 15) * 4;
            us4 kq = *(const us4*)(qkv + (r0 + r) * TRIPLE + kcol + f4);
            us4 vq = *(const us4*)(qkv + (r0 + r) * TRIPLE + vcol + f4);
#pragma unroll
            for (int j = 0; j < 4; ++j) { KT[f4 + j][r] = kq[j]; VT[f4 + j][r] = vq[j]; }
        }
        __syncthreads();
        int kg = wave * 32 + (lane >> 4) * 8;
        short8 af[4], bfr[4];
#pragma unroll
        for (int i = 0; i < 4; ++i) af[i]  = *(short8*)&KT[i*16 + lr][kg];
#pragma unroll
        for (int j = 0; j < 4; ++j) bfr[j] = *(short8*)&VT[j*16 + lr][kg];
#pragma unroll
        for (int i = 0; i < 4; ++i)
#pragma unroll
            for (int j = 0; j < 4; ++j)
                acc[i][j] = __builtin_amdgcn_mfma_f32_16x16x32_bf16(af[i], bfr[j], acc[i][j], 0, 0, 0);
        __syncthreads();
    }
    for (int w = 0; w < 4; ++w) {
        if (wave == w) {
#pragma unroll
            for (int i = 0; i < 4; ++i)
#pragma unroll
                for (int j = 0; j < 4; ++j)
#pragma unroll
                    for (int r = 0; r < 4; ++r) {
                        int m = i*16 + (lane >> 4) * 4 + r;
                        int d = j*16 + (lane & 15);
                        if (w == 0) red[m * 64 + d] = acc[i][j][r];
                        else        red[m * 64 + d] += acc[i][j][r];
                    }
        }
        __syncthreads();
    }
    float* kvout = kv + (size_t)bh * 4096;
#pragma unroll
    for (int i = 0; i < 16; ++i) {
        int idx = t + 256 * i;
        atomicAdd(&kvout[idx], red[idx]);
    }
}

// ---------------------------------------------------------------------------
// k_attn: attn = relu(q) @ kv per head (K=64), written in place over Q cols.
__global__ __launch_bounds__(256) void k_attn(unsigned short* __restrict__ qkv,
                                              const float* __restrict__ kv)
{
    __shared__ unsigned short Qh[128][72];
    __shared__ unsigned short kvT[64][72];
    int t = threadIdx.x, lane = t & 63, wave = t >> 6;
    size_t r0 = (size_t)blockIdx.x * 128;
    int b = (int)(r0 / N_);
    int lr = lane & 15;
    for (int h = 0; h < H_; ++h) {
#pragma unroll
        for (int i = 0; i < 8; ++i) {
            int c = t + 256 * i;
            int r = c >> 4, f4 = (c & 15) * 4;
            *(us4*)&Qh[r][f4] = *(const us4*)(qkv + (r0 + r) * TRIPLE + h * 64 + f4);
        }
        const float* kvh = kv + (size_t)(b * 8 + h) * 4096;
#pragma unroll
        for (int i = 0; i < 16; ++i) {
            int idx = t + 256 * i;
            int m = idx >> 6, d = idx & 63;
            kvT[d][m] = f2bf(kvh[idx]);
        }
        __syncthreads();
        f32x4 acc[2][4] = {};
#pragma unroll
        for (int ks = 0; ks < 2; ++ks) {
            int kg = ks * 32 + (lane >> 4) * 8;
            short8 af[2], bfr[4];
#pragma unroll
            for (int i = 0; i < 2; ++i) af[i]  = *(short8*)&Qh[wave*32 + i*16 + lr][kg];
#pragma unroll
            for (int j = 0; j < 4; ++j) bfr[j] = *(short8*)&kvT[j*16 + lr][kg];
#pragma unroll
            for (int i = 0; i < 2; ++i)
#pragma unroll
                for (int j = 0; j < 4; ++j)
                    acc[i][j] = __builtin_amdgcn_mfma_f32_16x16x32_bf16(af[i], bfr[j], acc[i][j], 0, 0, 0);
        }
        __syncthreads();
#pragma unroll
        for (int i = 0; i < 2; ++i)
#pragma unroll
            for (int j = 0; j < 4; ++j) {
                int row = wave*32 + i*16 + (lane >> 4) * 4;
                int col = h*64 + j*16 + (lane & 15);
#pragma unroll
                for (int r = 0; r < 4; ++r)
                    qkv[(r0 + row + r) * TRIPLE + col] = f2bf(acc[i][j][r]);
            }
    }
}

// ---------------------------------------------------------------------------
// k_out: LayerNorm(attn) @ w_out + b_out -> fp32 out.
__global__ __launch_bounds__(256) void k_out(const unsigned short* __restrict__ qkv,
        const unsigned short* __restrict__ woutT,
        const float* __restrict__ lnw, const float* __restrict__ lnb,
        const float* __restrict__ bout, float* __restrict__ out)
{
    __shared__ unsigned short As[128][40];
    __shared__ unsigned short Bs[128][40];
    __shared__ float mu[128], rs[128], lw[512], lb[512];
    int t = threadIdx.x, lane = t & 63, wave = t >> 6;
    int m0 = blockIdx.y * 128, n0 = blockIdx.x * 128;
    int wm = (wave & 1) * 64, wn = (wave >> 1) * 64;
    int lr = lane & 15, kg = (lane >> 4) * 8;

    for (int i = t; i < 512; i += 256) { lw[i] = lnw[i]; lb[i] = lnb[i]; }
    {
        int row = t >> 1, half = t & 1;
        const unsigned short* p = qkv + (size_t)(m0 + row) * TRIPLE + half * 256;
        float s = 0.0f, ss = 0.0f;
#pragma unroll 8
        for (int i = 0; i < 64; ++i) {
            us4 v = *(const us4*)(p + i * 4);
#pragma unroll
            for (int j = 0; j < 4; ++j) { float f = bf2f(v[j]); s += f; ss += f * f; }
        }
        s  += __shfl_xor(s, 1);
        ss += __shfl_xor(ss, 1);
        if (half == 0) {
            float m = s * (1.0f / 512.0f);
            float var = ss * (1.0f / 512.0f) - m * m;
            mu[row] = m;
            rs[row] = rsqrtf(var + EPS_);
        }
    }
    __syncthreads();

    f32x4 acc[4][4] = {};
    for (int k0 = 0; k0 < 512; k0 += 32) {
#pragma unroll
        for (int i = 0; i < 4; ++i) {
            int c = t + 256 * i;
            int r = c >> 3, c4 = (c & 7) * 4;
            us4 v = *(const us4*)(qkv + (size_t)(m0 + r) * TRIPLE + k0 + c4);
            float mm = mu[r], rr = rs[r];
            unsigned short* dst = &As[r][c4];
#pragma unroll
            for (int j = 0; j < 4; ++j) {
                float f = (bf2f(v[j]) - mm) * rr * lw[k0 + c4 + j] + lb[k0 + c4 + j];
                dst[j] = f2bf(f);
            }
        }
#pragma unroll
        for (int i = 0; i < 2; ++i) {
            int c = t + 256 * i;
            int r = c >> 2, c8 = (c & 3) * 8;
            *(int4*)&Bs[r][c8] = *(const int4*)(woutT + (size_t)(n0 + r) * DIM_ + k0 + c8);
        }
        __syncthreads();
        short8 af[4], bfr[4];
#pragma unroll
        for (int i = 0; i < 4; ++i) af[i]  = *(short8*)&As[wm + i*16 + lr][kg];
#pragma unroll
        for (int j = 0; j < 4; ++j) bfr[j] = *(short8*)&Bs[wn + j*16 + lr][kg];
#pragma unroll
        for (int i = 0; i < 4; ++i)
#pragma unroll
            for (int j = 0; j < 4; ++j)
                acc[i][j] = __builtin_amdgcn_mfma_f32_16x16x32_bf16(af[i], bfr[j], acc[i][j], 0, 0, 0);
        __syncthreads();
    }
#pragma unroll
    for (int i = 0; i < 4; ++i) {
        int row = m0 + wm + i*16 + (lane >> 4) * 4;
#pragma unroll
        for (int j = 0; j < 4; ++j) {
            int col = n0 + wn + j*16 + (lane & 15);
            float bo = bout[col];
#pragma unroll
            for (int r = 0; r < 4; ++r)
                out[(size_t)(row + r) * DIM_ + col] = acc[i][j][r] + bo;
        }
    }
}

// ---------------------------------------------------------------------------
extern "C" void kernel_launch(void* const* d_in, const int* in_sizes, int n_in,
                              void* d_out, int out_size, void* d_ws, size_t ws_size,
                              hipStream_t stream) {
    (void)in_sizes; (void)n_in; (void)out_size;
    const float* x     = (const float*)d_in[0];
    const float* w_qkv = (const float*)d_in[1];
    const float* ln_w  = (const float*)d_in[2];
    const float* ln_b  = (const float*)d_in[3];
    const float* w_out = (const float*)d_in[4];
    const float* b_out = (const float*)d_in[5];
    float* out = (float*)d_out;

    char* ws = (char*)d_ws;
    const size_t QKV_BYTES = (size_t)ROWS * TRIPLE * sizeof(unsigned short); // 201326592
    const size_t KV_BYTES  = (size_t)64 * 64 * 64 * sizeof(float);           // 1048576
    const size_t WQT_BYTES = (size_t)TRIPLE * DIM_ * sizeof(unsigned short); // 1572864
    const size_t WOT_BYTES = (size_t)DIM_ * DIM_ * sizeof(unsigned short);   // 524288
    const size_t XB_BYTES  = (size_t)ROWS * DIM_ * sizeof(unsigned short);   // 67108864
    unsigned short* qkv   = (unsigned short*)ws;
    float*          kvbuf = (float*)(ws + QKV_BYTES);
    unsigned short* wqkvT = (unsigned short*)(ws + QKV_BYTES + KV_BYTES);
    unsigned short* woutT = (unsigned short*)(ws + QKV_BYTES + KV_BYTES + WQT_BYTES);
    unsigned short* xb    = (unsigned short*)(ws + QKV_BYTES + KV_BYTES + WQT_BYTES + WOT_BYTES);
    const size_t NEED = QKV_BYTES + KV_BYTES + WQT_BYTES + WOT_BYTES + XB_BYTES;

    hipMemsetAsync(kvbuf, 0, KV_BYTES, stream);
    k_prep<<<3072, 256, 0, stream>>>(w_qkv, w_out, wqkvT, woutT);
    if (ws_size >= NEED) {
        k_cvt<<<16384, 256, 0, stream>>>(x, xb);
        k_qkv8<<<dim3(1536), 512, 0, stream>>>(xb, wqkvT, qkv);
    } else {
        k_qkv_f<<<dim3(12, 512), 256, 0, stream>>>(x, wqkvT, qkv);
    }
    k_kv<<<dim3(64, 8), 256, 0, stream>>>(qkv, kvbuf);
    k_attn<<<512, 256, 0, stream>>>(qkv, kvbuf);
    k_out<<<dim3(4, 512), 256, 0, stream>>>(qkv, woutT, ln_w, ln_b, b_out, out);
}